// Round 1
// baseline (347.968 us; speedup 1.0000x reference)
//
#include <hip/hip_runtime.h>
#include <cstdint>
#include <cstddef>

// B=1024 batches, P=64 patches, C=512 channels. res = X + MLP_patch(X), then LN over C.
#define BB 1024
#define PP 64
#define CC 512
constexpr float LN_EPS = 1e-5f;

// MFMA fragment types (guide §3: short8 = 8 bf16 in 4 VGPRs, float4 acc)
typedef short  s16x8 __attribute__((ext_vector_type(8)));
typedef float  f32x4 __attribute__((ext_vector_type(4)));
typedef unsigned int u32x2 __attribute__((ext_vector_type(2)));

__device__ __forceinline__ unsigned cvt_pk_bf16(float lo, float hi) {
    unsigned r;
    asm("v_cvt_pk_bf16_f32 %0, %1, %2" : "=v"(r) : "v"(lo), "v"(hi));  // RNE on gfx950
    return r;
}
__device__ __forceinline__ float bflo(unsigned u) { union { unsigned u; float f; } v; v.u = u << 16;          return v.f; }
__device__ __forceinline__ float bfhi(unsigned u) { union { unsigned u; float f; } v; v.u = u & 0xffff0000u;  return v.f; }

// 8 consecutive fp32 -> bf16 fragment (A/B layouts are lane-identical on gfx950)
__device__ __forceinline__ s16x8 ldwf(const float* p) {
    float4 a = *(const float4*)p;
    float4 b = *(const float4*)(p + 4);
    union { s16x8 v; unsigned u[4]; } r;
    r.u[0] = cvt_pk_bf16(a.x, a.y);
    r.u[1] = cvt_pk_bf16(a.z, a.w);
    r.u[2] = cvt_pk_bf16(b.x, b.y);
    r.u[3] = cvt_pk_bf16(b.z, b.w);
    return r.v;
}

__device__ __forceinline__ float gelu_t(float t) {
    float sg = 1.5957691216f * (t + 0.044715f * t * t * t);
    return t / (1.0f + __expf(-sg));
}

// Block: 256 threads = 4 waves; wave w owns channel c0+w; 128 batches in 8 subtiles of 16.
// R2 redesign: SWAPPED MFMA operands (mfma(W, X)): acc lanes hold b=lane&15, q=4*lq+r
// (q-contiguous per lane) -> H handoff is 4x ds_write_b64 + wave-private lgkm wait (no
// barrier), residual is 4x ds_read_b64, RS writes are 4x ds_write_b128. 2 barriers/subtile
// (was 4). T14: next subtile's X loads issued right after B1, consumed next iteration.
__global__ __launch_bounds__(256, 2) void k_mix(
    const float* __restrict__ X,  const float* __restrict__ W1,
    const float* __restrict__ B1, const float* __restrict__ W2,
    const float* __restrict__ B2, float* __restrict__ OUT)
{
    // XS/HS: bf16 [c-plane][b 16][p/q 64 pad->72]; 144 B rows keep 16-B alignment for
    // ds_read_b128 and stagger banks. RS: fp32 [c*16+b][q 64 pad->68] -> b128 writes
    // 16B-aligned, gather reads lane-consecutive (conflict-free).
    __shared__ __align__(16) unsigned short XS[4][16][72];   // 9216 B
    __shared__ __align__(16) unsigned short HS[4][16][72];   // 9216 B
    __shared__ __align__(16) float RS[64][68];               // 17408 B

    const int tid  = threadIdx.x;
    const int lane = tid & 63;
    const int wv   = tid >> 6;        // wave -> channel offset
    const int lb   = lane & 15;       // acc col: b-index
    const int lq   = lane >> 4;       // k-quad / acc row-quad

    // XCD swizzle: gid&7 = XCD. Each XCD gets a contiguous 64-channel range so the
    // 16 B/line X reads / OUT writes merge in its L2.
    const int gid  = blockIdx.x;
    const int xcd  = gid & 7, slot = gid >> 3;     // slot 0..127
    const int cg   = xcd * 16 + (slot & 15);       // 0..127 c-group (4 ch)
    const int bt   = slot >> 4;                    // 0..7 b-tile
    const int c0   = cg * 4, b0 = bt * 128;
    const int c    = c0 + wv;

    // ---- W1/W2 fragments (used as A-operand now; same lane layout as before) ----
    const float* w1c = W1 + (size_t)c * 4096;
    const float* w2c = W2 + (size_t)c * 4096;
    const int wq = lb * 64 + lq * 8;    // W[c][q=mt*16+lb][p=ks*32+lq*8+j]
    s16x8 w1_0_0 = ldwf(w1c +    0 + wq), w1_0_1 = ldwf(w1c +    0 + wq + 32);
    s16x8 w1_1_0 = ldwf(w1c + 1024 + wq), w1_1_1 = ldwf(w1c + 1024 + wq + 32);
    s16x8 w1_2_0 = ldwf(w1c + 2048 + wq), w1_2_1 = ldwf(w1c + 2048 + wq + 32);
    s16x8 w1_3_0 = ldwf(w1c + 3072 + wq), w1_3_1 = ldwf(w1c + 3072 + wq + 32);
    s16x8 w2_0_0 = ldwf(w2c +    0 + wq), w2_0_1 = ldwf(w2c +    0 + wq + 32);
    s16x8 w2_1_0 = ldwf(w2c + 1024 + wq), w2_1_1 = ldwf(w2c + 1024 + wq + 32);
    s16x8 w2_2_0 = ldwf(w2c + 2048 + wq), w2_2_1 = ldwf(w2c + 2048 + wq + 32);
    s16x8 w2_3_0 = ldwf(w2c + 3072 + wq), w2_3_1 = ldwf(w2c + 3072 + wq + 32);
    // biases: acc rows are q = mt*16 + lq*4 + r -> float4 per mt
    const float4 b1_0 = *(const float4*)(B1 + c * 64 +  0 + lq * 4);
    const float4 b1_1 = *(const float4*)(B1 + c * 64 + 16 + lq * 4);
    const float4 b1_2 = *(const float4*)(B1 + c * 64 + 32 + lq * 4);
    const float4 b1_3 = *(const float4*)(B1 + c * 64 + 48 + lq * 4);
    const float4 b2_0 = *(const float4*)(B2 + c * 64 +  0 + lq * 4);
    const float4 b2_1 = *(const float4*)(B2 + c * 64 + 16 + lq * 4);
    const float4 b2_2 = *(const float4*)(B2 + c * 64 + 32 + lq * 4);
    const float4 b2_3 = *(const float4*)(B2 + c * 64 + 48 + lq * 4);

    const unsigned short* xp = &XS[wv][0][0];
    unsigned short*       hp = &HS[wv][0][0];

    // ---- T14 prologue: issue subtile-0 X loads into regs ----
    float4 r0[2], r1[2];
    #pragma unroll
    for (int it = 0; it < 2; ++it) {
        int pi = it * 256 + tid;              // 512 (b, p-pair) units
        int b = pi >> 5, p2 = pi & 31;
        const float* src = X + ((size_t)(b0 + b) * PP + 2 * p2) * CC + c0;
        r0[it] = *(const float4*)src;
        r1[it] = *(const float4*)(src + CC);
    }

    for (int s = 0; s < 8; ++s) {
        const int bb = b0 + s * 16;

        // ---- write staged regs -> XS bf16 (transpose); pairs (p even, p odd) packed ----
        #pragma unroll
        for (int it = 0; it < 2; ++it) {
            int pi = it * 256 + tid;
            int b = pi >> 5, p2 = pi & 31;
            *(unsigned*)&XS[0][b][2 * p2] = cvt_pk_bf16(r0[it].x, r1[it].x);
            *(unsigned*)&XS[1][b][2 * p2] = cvt_pk_bf16(r0[it].y, r1[it].y);
            *(unsigned*)&XS[2][b][2 * p2] = cvt_pk_bf16(r0[it].z, r1[it].z);
            *(unsigned*)&XS[3][b][2 * p2] = cvt_pk_bf16(r0[it].w, r1[it].w);
        }
        __syncthreads();                                   // B1: cross-wave XS handoff

        // ---- T14: issue next subtile's loads now; latency hides under both GEMMs ----
        if (s < 7) {
            #pragma unroll
            for (int it = 0; it < 2; ++it) {
                int pi = it * 256 + tid;
                int b = pi >> 5, p2 = pi & 31;
                const float* src = X + ((size_t)(bb + 16 + b) * PP + 2 * p2) * CC + c0;
                r0[it] = *(const float4*)src;
                r1[it] = *(const float4*)(src + CC);
            }
        }

        // ---- X fragments (B-operand): lane holds X[b=lb][p=lq*8+j (+32)] ----
        s16x8 xf0 = *(const s16x8*)(xp + lb * 72 +  0 + lq * 8);
        s16x8 xf1 = *(const s16x8*)(xp + lb * 72 + 32 + lq * 8);

        // ---- GEMM1 swapped: acc = W1 x X -> lane (b=lb, q=mt*16+lq*4+r); GELU; pack ----
        #define DO1(mt) { \
            f32x4 a = {b1_##mt.x, b1_##mt.y, b1_##mt.z, b1_##mt.w}; \
            a = __builtin_amdgcn_mfma_f32_16x16x32_bf16(w1_##mt##_0, xf0, a, 0, 0, 0); \
            a = __builtin_amdgcn_mfma_f32_16x16x32_bf16(w1_##mt##_1, xf1, a, 0, 0, 0); \
            u32x2 h; \
            h[0] = cvt_pk_bf16(gelu_t(a[0]), gelu_t(a[1])); \
            h[1] = cvt_pk_bf16(gelu_t(a[2]), gelu_t(a[3])); \
            *(u32x2*)(hp + lb * 72 + mt * 16 + lq * 4) = h; }   /* ds_write_b64 */
        DO1(0) DO1(1) DO1(2) DO1(3)
        #undef DO1

        // HS plane is wave-private: drain DS ops instead of a block barrier.
        asm volatile("s_waitcnt lgkmcnt(0)" ::: "memory");

        // ---- H fragments (B-operand): lane holds H[b=lb][q=lq*8+j (+32)] ----
        s16x8 hf0 = *(const s16x8*)(hp + lb * 72 +  0 + lq * 8);
        s16x8 hf1 = *(const s16x8*)(hp + lb * 72 + 32 + lq * 8);

        // ---- GEMM2 swapped + bias + residual (b64 read from XS) -> RS (b128 write) ----
        #define DO2(mt) { \
            f32x4 a = {b2_##mt.x, b2_##mt.y, b2_##mt.z, b2_##mt.w}; \
            a = __builtin_amdgcn_mfma_f32_16x16x32_bf16(w2_##mt##_0, hf0, a, 0, 0, 0); \
            a = __builtin_amdgcn_mfma_f32_16x16x32_bf16(w2_##mt##_1, hf1, a, 0, 0, 0); \
            u32x2 xv = *(const u32x2*)(xp + lb * 72 + mt * 16 + lq * 4); \
            a[0] += bflo(xv[0]); a[1] += bfhi(xv[0]); \
            a[2] += bflo(xv[1]); a[3] += bfhi(xv[1]); \
            *(f32x4*)&RS[wv * 16 + lb][mt * 16 + lq * 4] = a; }
        DO2(0) DO2(1) DO2(2) DO2(3)
        #undef DO2
        __syncthreads();                                   // B3: cross-wave RS handoff

        // ---- gather RS -> 16 B-granule stores (L2 merges via XCD swizzle) ----
        // No trailing barrier: gather reads precede next B1, which precedes next RS
        // writes; XS (written between B3 and B1) is disjoint from RS.
        #pragma unroll
        for (int it = 0; it < 4; ++it) {
            int fi = it * 256 + tid;          // 1024 (b,q) rows; per-wave b fixed, q=lane
            int q = fi & 63, b = fi >> 6;
            float4 v = { RS[b][q], RS[16 + b][q], RS[32 + b][q], RS[48 + b][q] };
            *(float4*)(OUT + ((size_t)(bb + b) * PP + q) * CC + c0) = v;
        }
    }
}

// LayerNorm over channels: one wave per (b,p) row (512 ch = 64 lanes x 2 float4).
__global__ __launch_bounds__(256) void k_ln(
    float* __restrict__ OUT, const float* __restrict__ G, const float* __restrict__ Be)
{
    const int lane = threadIdx.x & 63;
    const int m    = blockIdx.x * 4 + (threadIdx.x >> 6);
    float4* row = (float4*)(OUT + (size_t)m * CC);
    float4 v0 = row[lane], v1 = row[lane + 64];
    float s = (v0.x + v0.y) + (v0.z + v0.w) + (v1.x + v1.y) + (v1.z + v1.w);
    float q = (v0.x * v0.x + v0.y * v0.y) + (v0.z * v0.z + v0.w * v0.w)
            + (v1.x * v1.x + v1.y * v1.y) + (v1.z * v1.z + v1.w * v1.w);
    #pragma unroll
    for (int o = 32; o >= 1; o >>= 1) {
        s += __shfl_xor(s, o, 64);
        q += __shfl_xor(q, o, 64);
    }
    const float mu  = s * (1.0f / CC);
    const float var = q * (1.0f / CC) - mu * mu;
    const float inv = rsqrtf(var + LN_EPS);
    const float4 g0 = ((const float4*)G)[lane],  g1 = ((const float4*)G)[lane + 64];
    const float4 e0 = ((const float4*)Be)[lane], e1 = ((const float4*)Be)[lane + 64];
    v0.x = (v0.x - mu) * inv * g0.x + e0.x;  v0.y = (v0.y - mu) * inv * g0.y + e0.y;
    v0.z = (v0.z - mu) * inv * g0.z + e0.z;  v0.w = (v0.w - mu) * inv * g0.w + e0.w;
    v1.x = (v1.x - mu) * inv * g1.x + e1.x;  v1.y = (v1.y - mu) * inv * g1.y + e1.y;
    v1.z = (v1.z - mu) * inv * g1.z + e1.z;  v1.w = (v1.w - mu) * inv * g1.w + e1.w;
    row[lane] = v0; row[lane + 64] = v1;
}

extern "C" void kernel_launch(void* const* d_in, const int* in_sizes, int n_in,
                              void* d_out, int out_size, void* d_ws, size_t ws_size,
                              hipStream_t stream) {
    const float* X  = (const float*)d_in[0];
    const float* W1 = (const float*)d_in[1];
    const float* B1 = (const float*)d_in[2];
    const float* W2 = (const float*)d_in[3];
    const float* B2 = (const float*)d_in[4];
    const float* G  = (const float*)d_in[5];
    const float* Be = (const float*)d_in[6];
    float* OUT = (float*)d_out;

    k_mix<<<1024, 256, 0, stream>>>(X, W1, B1, W2, B2, OUT);       // 128 c-grp x 8 b-tile
    k_ln<<<(BB * PP) / 4, 256, 0, stream>>>(OUT, G, Be);           // 65536 rows / 4
}

// Round 2
// 340.317 us; speedup vs baseline: 1.0225x; 1.0225x over previous
//
#include <hip/hip_runtime.h>
#include <cstdint>
#include <cstddef>

// B=1024 batches, P=64 patches, C=512 channels. res = X + MLP_patch(X), then LN over C.
#define BB 1024
#define PP 64
#define CC 512
constexpr float LN_EPS = 1e-5f;

// MFMA fragment types (guide §3: short8 = 8 bf16 in 4 VGPRs, float4 acc)
typedef short  s16x8 __attribute__((ext_vector_type(8)));
typedef float  f32x4 __attribute__((ext_vector_type(4)));
typedef unsigned int u32x2 __attribute__((ext_vector_type(2)));

__device__ __forceinline__ unsigned cvt_pk_bf16(float lo, float hi) {
    unsigned r;
    asm("v_cvt_pk_bf16_f32 %0, %1, %2" : "=v"(r) : "v"(lo), "v"(hi));  // RNE on gfx950
    return r;
}
__device__ __forceinline__ float bflo(unsigned u) { union { unsigned u; float f; } v; v.u = u << 16;          return v.f; }
__device__ __forceinline__ float bfhi(unsigned u) { union { unsigned u; float f; } v; v.u = u & 0xffff0000u;  return v.f; }

// 8 consecutive fp32 -> bf16 fragment (A/B layouts are lane-identical on gfx950)
__device__ __forceinline__ s16x8 ldwf(const float* p) {
    float4 a = *(const float4*)p;
    float4 b = *(const float4*)(p + 4);
    union { s16x8 v; unsigned u[4]; } r;
    r.u[0] = cvt_pk_bf16(a.x, a.y);
    r.u[1] = cvt_pk_bf16(a.z, a.w);
    r.u[2] = cvt_pk_bf16(b.x, b.y);
    r.u[3] = cvt_pk_bf16(b.z, b.w);
    return r.v;
}

__device__ __forceinline__ float gelu_t(float t) {
    float sg = 1.5957691216f * (t + 0.044715f * t * t * t);
    return t / (1.0f + __expf(-sg));
}

// R2 theory: R1 was L2-TRANSACTION-bound (16 B/row granule -> 64 lines per wave memop;
// MfmaUtil 2.3 / VALU 15 / hbm 28% all idle). Fix: 16 channels per block (one per wave,
// 16 waves = 1024 threads) -> X loads and OUT stores are 64-B-sector-dense (4x fewer
// txns). Weights stay register-resident per wave. Grid 256 = 1 block/CU; gid=bt*32+cg
// pins c-group to XCD (gid%8 == cg%8) so each XCD's 2 MB weight slice is L2-resident.
__global__ __launch_bounds__(1024) void k_mix(
    const float* __restrict__ X,  const float* __restrict__ W1,
    const float* __restrict__ B1, const float* __restrict__ W2,
    const float* __restrict__ B2, float* __restrict__ OUT)
{
    // XS: bf16 [16 c-planes][16 b][64 p pad->72]; plane stride 1160 shorts = 2320 B
    // (16B-aligned; 580 words ≡ 4 mod 32 de-conflicts the 4-plane staging writes to
    // 2-way). HS: wave-private planes, stride 1152 shorts. RS: fp32 [b][c][q] with
    // q-dim padded 64->68 and b-stride 1092 words (both ≡ 4 mod 32): per-lane f32x4
    // writes land on 8 rotating bank-groups, store-pass scalar reads are 2-way.
    __shared__ __align__(16) unsigned short XS[16 * 1160];   // 37120 B
    __shared__ __align__(16) unsigned short HS[16 * 1152];   // 36864 B
    __shared__ __align__(16) float          RS[16 * 1092];   // 69888 B
    __shared__ __align__(16) float          BS[16 * 128];    //  8192 B (biases)

    const int tid  = threadIdx.x;
    const int lane = tid & 63;
    const int wv   = tid >> 6;        // wave -> channel offset (0..15)
    const int lb   = lane & 15;       // acc col: b-index
    const int lq   = lane >> 4;       // k-quad / acc row-quad

    const int gid = blockIdx.x;
    const int cg  = gid & 31;         // c-group: XCD = gid%8 = cg%8 (weights L2-pinned)
    const int bt  = gid >> 5;         // 0..7 b-tile
    const int c0  = cg * 16, b0 = bt * 128;
    const int c   = c0 + wv;

    // ---- W1/W2 fragments resident in regs for the whole block (A-operand) ----
    const float* w1c = W1 + (size_t)c * 4096;
    const float* w2c = W2 + (size_t)c * 4096;
    const int wq = lb * 64 + lq * 8;    // W[c][q=mt*16+lb][p=ks*32+lq*8+j]
    s16x8 w1_0_0 = ldwf(w1c +    0 + wq), w1_0_1 = ldwf(w1c +    0 + wq + 32);
    s16x8 w1_1_0 = ldwf(w1c + 1024 + wq), w1_1_1 = ldwf(w1c + 1024 + wq + 32);
    s16x8 w1_2_0 = ldwf(w1c + 2048 + wq), w1_2_1 = ldwf(w1c + 2048 + wq + 32);
    s16x8 w1_3_0 = ldwf(w1c + 3072 + wq), w1_3_1 = ldwf(w1c + 3072 + wq + 32);
    s16x8 w2_0_0 = ldwf(w2c +    0 + wq), w2_0_1 = ldwf(w2c +    0 + wq + 32);
    s16x8 w2_1_0 = ldwf(w2c + 1024 + wq), w2_1_1 = ldwf(w2c + 1024 + wq + 32);
    s16x8 w2_2_0 = ldwf(w2c + 2048 + wq), w2_2_1 = ldwf(w2c + 2048 + wq + 32);
    s16x8 w2_3_0 = ldwf(w2c + 3072 + wq), w2_3_1 = ldwf(w2c + 3072 + wq + 32);

    // biases -> LDS (saves 32 VGPR vs resident float4s; reads below are broadcast)
    BS[wv * 128 +      lane] = B1[c * 64 + lane];
    BS[wv * 128 + 64 + lane] = B2[c * 64 + lane];

    const unsigned short* xp = &XS[wv * 1160];
    unsigned short*       hp = &HS[wv * 1152];

    // staging mapping: task = (b, p-pair, c-quad); lanes 0..3 cover one 64-B row chunk
    const int sc4 = tid & 3;            // c-quad within the 16-channel slice
    const int sp2 = (tid >> 2) & 31;    // p-pair
    const int sbo = tid >> 7;           // b offset (0..7); + pass*8

    // ---- T14 prologue: issue subtile-0 X loads into regs ----
    float4 r0[2], r1[2];
    #pragma unroll
    for (int pass = 0; pass < 2; ++pass) {
        const float* src = X + ((size_t)(b0 + pass * 8 + sbo) * PP + 2 * sp2) * CC
                             + c0 + sc4 * 4;
        r0[pass] = *(const float4*)src;
        r1[pass] = *(const float4*)(src + CC);
    }

    for (int s = 0; s < 8; ++s) {
        const int bb = b0 + s * 16;

        // ---- write staged regs -> XS bf16 (transpose); (p even, p odd) packed ----
        #pragma unroll
        for (int pass = 0; pass < 2; ++pass) {
            int b = pass * 8 + sbo;
            *(unsigned*)&XS[(sc4 * 4 + 0) * 1160 + b * 72 + 2 * sp2] = cvt_pk_bf16(r0[pass].x, r1[pass].x);
            *(unsigned*)&XS[(sc4 * 4 + 1) * 1160 + b * 72 + 2 * sp2] = cvt_pk_bf16(r0[pass].y, r1[pass].y);
            *(unsigned*)&XS[(sc4 * 4 + 2) * 1160 + b * 72 + 2 * sp2] = cvt_pk_bf16(r0[pass].z, r1[pass].z);
            *(unsigned*)&XS[(sc4 * 4 + 3) * 1160 + b * 72 + 2 * sp2] = cvt_pk_bf16(r0[pass].w, r1[pass].w);
        }
        __syncthreads();                                   // B1: XS (+ first-iter BS) handoff

        // ---- T14: issue next subtile's loads; latency hides under both GEMMs ----
        if (s < 7) {
            #pragma unroll
            for (int pass = 0; pass < 2; ++pass) {
                const float* src = X + ((size_t)(bb + 16 + pass * 8 + sbo) * PP + 2 * sp2) * CC
                                     + c0 + sc4 * 4;
                r0[pass] = *(const float4*)src;
                r1[pass] = *(const float4*)(src + CC);
            }
        }

        // ---- X fragments (B-operand): lane holds X[b=lb][p=lq*8+j (+32)] ----
        s16x8 xf0 = *(const s16x8*)(xp + lb * 72 +  0 + lq * 8);
        s16x8 xf1 = *(const s16x8*)(xp + lb * 72 + 32 + lq * 8);

        // ---- GEMM1 swapped: acc = W1 x X -> lane (b=lb, q=mt*16+lq*4+r); GELU ----
        #define DO1(mt) { \
            float4 bv = *(const float4*)&BS[wv * 128 + mt * 16 + lq * 4]; \
            f32x4 a = {bv.x, bv.y, bv.z, bv.w}; \
            a = __builtin_amdgcn_mfma_f32_16x16x32_bf16(w1_##mt##_0, xf0, a, 0, 0, 0); \
            a = __builtin_amdgcn_mfma_f32_16x16x32_bf16(w1_##mt##_1, xf1, a, 0, 0, 0); \
            u32x2 h; \
            h[0] = cvt_pk_bf16(gelu_t(a[0]), gelu_t(a[1])); \
            h[1] = cvt_pk_bf16(gelu_t(a[2]), gelu_t(a[3])); \
            *(u32x2*)(hp + lb * 72 + mt * 16 + lq * 4) = h; }   /* ds_write_b64 */
        DO1(0) DO1(1) DO1(2) DO1(3)
        #undef DO1

        // HS plane is wave-private: drain DS ops instead of a block barrier.
        asm volatile("s_waitcnt lgkmcnt(0)" ::: "memory");

        // ---- H fragments (B-operand) ----
        s16x8 hf0 = *(const s16x8*)(hp + lb * 72 +  0 + lq * 8);
        s16x8 hf1 = *(const s16x8*)(hp + lb * 72 + 32 + lq * 8);

        // ---- GEMM2 swapped + bias + residual (b64 from XS) -> RS [b][c][q] b128 ----
        #define DO2(mt) { \
            float4 bv = *(const float4*)&BS[wv * 128 + 64 + mt * 16 + lq * 4]; \
            f32x4 a = {bv.x, bv.y, bv.z, bv.w}; \
            a = __builtin_amdgcn_mfma_f32_16x16x32_bf16(w2_##mt##_0, hf0, a, 0, 0, 0); \
            a = __builtin_amdgcn_mfma_f32_16x16x32_bf16(w2_##mt##_1, hf1, a, 0, 0, 0); \
            u32x2 xv = *(const u32x2*)(xp + lb * 72 + mt * 16 + lq * 4); \
            a[0] += bflo(xv[0]); a[1] += bfhi(xv[0]); \
            a[2] += bflo(xv[1]); a[3] += bfhi(xv[1]); \
            *(f32x4*)&RS[lb * 1092 + wv * 68 + mt * 16 + lq * 4] = a; }
        DO2(0) DO2(1) DO2(2) DO2(3)
        #undef DO2
        __syncthreads();                                   // B2: cross-wave RS handoff

        // ---- gather RS -> 64-B-dense stores (4 lanes cover one row's 16 channels) ----
        // No trailing barrier: RS reads precede next B1, which precedes next RS writes;
        // XS (written between B2 and B1) is disjoint from RS.
        #pragma unroll
        for (int it = 0; it < 4; ++it) {
            int fi = it * 1024 + tid;          // (b, q, c-quad): 16*64*4 = 4096 tasks
            int c4 = fi & 3, q = (fi >> 2) & 63, b = fi >> 8;
            const float* rp = &RS[b * 1092 + c4 * 4 * 68 + q];
            float4 v = { rp[0], rp[68], rp[136], rp[204] };
            *(float4*)(OUT + ((size_t)(bb + b) * PP + q) * CC + c0 + c4 * 4) = v;
        }
    }
}

// LayerNorm over channels: one wave per (b,p) row (512 ch = 64 lanes x 2 float4).
__global__ __launch_bounds__(256) void k_ln(
    float* __restrict__ OUT, const float* __restrict__ G, const float* __restrict__ Be)
{
    const int lane = threadIdx.x & 63;
    const int m    = blockIdx.x * 4 + (threadIdx.x >> 6);
    float4* row = (float4*)(OUT + (size_t)m * CC);
    float4 v0 = row[lane], v1 = row[lane + 64];
    float s = (v0.x + v0.y) + (v0.z + v0.w) + (v1.x + v1.y) + (v1.z + v1.w);
    float q = (v0.x * v0.x + v0.y * v0.y) + (v0.z * v0.z + v0.w * v0.w)
            + (v1.x * v1.x + v1.y * v1.y) + (v1.z * v1.z + v1.w * v1.w);
    #pragma unroll
    for (int o = 32; o >= 1; o >>= 1) {
        s += __shfl_xor(s, o, 64);
        q += __shfl_xor(q, o, 64);
    }
    const float mu  = s * (1.0f / CC);
    const float var = q * (1.0f / CC) - mu * mu;
    const float inv = rsqrtf(var + LN_EPS);
    const float4 g0 = ((const float4*)G)[lane],  g1 = ((const float4*)G)[lane + 64];
    const float4 e0 = ((const float4*)Be)[lane], e1 = ((const float4*)Be)[lane + 64];
    v0.x = (v0.x - mu) * inv * g0.x + e0.x;  v0.y = (v0.y - mu) * inv * g0.y + e0.y;
    v0.z = (v0.z - mu) * inv * g0.z + e0.z;  v0.w = (v0.w - mu) * inv * g0.w + e0.w;
    v1.x = (v1.x - mu) * inv * g1.x + e1.x;  v1.y = (v1.y - mu) * inv * g1.y + e1.y;
    v1.z = (v1.z - mu) * inv * g1.z + e1.z;  v1.w = (v1.w - mu) * inv * g1.w + e1.w;
    row[lane] = v0; row[lane + 64] = v1;
}

extern "C" void kernel_launch(void* const* d_in, const int* in_sizes, int n_in,
                              void* d_out, int out_size, void* d_ws, size_t ws_size,
                              hipStream_t stream) {
    const float* X  = (const float*)d_in[0];
    const float* W1 = (const float*)d_in[1];
    const float* B1 = (const float*)d_in[2];
    const float* W2 = (const float*)d_in[3];
    const float* B2 = (const float*)d_in[4];
    const float* G  = (const float*)d_in[5];
    const float* Be = (const float*)d_in[6];
    float* OUT = (float*)d_out;

    k_mix<<<256, 1024, 0, stream>>>(X, W1, B1, W2, B2, OUT);       // 32 c-grp x 8 b-tile
    k_ln<<<(BB * PP) / 4, 256, 0, stream>>>(OUT, G, Be);           // 65536 rows / 4
}